// Round 3
// baseline (124.379 us; speedup 1.0000x reference)
//
#include <hip/hip_runtime.h>
#include <math.h>

#define D_INNER 1024
#define STATE   16
#define DT_RANK 64
#define NPROJ   96
#define LSEQ    1024
#define NBATCH  2

// ============ Kernel 1: proj = x @ W_xproj ============
// 256 blocks x 768 threads; 8 rows/block, K split across 8 groups of 128.
__global__ __launch_bounds__(768) void proj_kernel(
        const float* __restrict__ x, const float* __restrict__ Wx,
        float* __restrict__ projdt, float* __restrict__ Bg, float* __restrict__ Cg) {
    const int tid = threadIdx.x;
    const int j  = tid % 96;
    const int kq = tid / 96;              // 0..7
    const int row0 = blockIdx.x * 8;

    const float* wp = Wx + (size_t)(kq * 128) * 96 + j;
    const float* xb = x + (size_t)row0 * 1024 + kq * 128;

    float a[8];
    #pragma unroll
    for (int r = 0; r < 8; ++r) a[r] = 0.f;

    #pragma unroll 4
    for (int k = 0; k < 128; k += 4) {
        float4 xr[8];
        #pragma unroll
        for (int r = 0; r < 8; ++r)
            xr[r] = *(const float4*)(xb + (size_t)r * 1024 + k);
        #pragma unroll
        for (int kk = 0; kk < 4; ++kk) {
            float w = wp[(size_t)(k + kk) * 96];
            #pragma unroll
            for (int r = 0; r < 8; ++r) {
                float xv = (kk == 0) ? xr[r].x : (kk == 1) ? xr[r].y
                         : (kk == 2) ? xr[r].z : xr[r].w;
                a[r] = fmaf(xv, w, a[r]);
            }
        }
    }

    __shared__ float red[8][8][96];       // [kq][r][j] = 24 KB
    #pragma unroll
    for (int r = 0; r < 8; ++r) red[kq][r][j] = a[r];
    __syncthreads();

    {   // 768 outputs, one per thread
        const int r  = tid / 96;
        const int jj = tid % 96;
        float s = 0.f;
        #pragma unroll
        for (int p = 0; p < 8; ++p) s += red[p][r][jj];
        const int row = row0 + r;
        const int b = row >> 10, l = row & 1023;
        if (jj < 64)      projdt[(size_t)row * 64 + jj] = s;
        else if (jj < 80) Bg[((size_t)b * 16 + (jj - 64)) * 1024 + l] = s;
        else              Cg[((size_t)b * 16 + (jj - 80)) * 1024 + l] = s;
    }
}

// ============ Kernel 2: delta = softplus(projdt @ W_dt + b_dt), transposed out ====
__global__ __launch_bounds__(256) void delta_kernel(
        const float* __restrict__ projdt, const float* __restrict__ Wdt,
        const float* __restrict__ bdt, float* __restrict__ delta_t) {
    const int bid = blockIdx.x;
    const int lt = bid >> 4;
    const int dt = bid & 15;
    const int row0 = lt * 64;
    const int d0 = dt * 64;
    const int tid = threadIdx.x;

    __shared__ float pl[64][69];
    __shared__ float wl[64][68];
    __shared__ float dtile[64][65];

    {
        const float4* src = (const float4*)(projdt + (size_t)row0 * 64);
        #pragma unroll
        for (int i = 0; i < 4; ++i) {
            int f4i = tid + 256 * i;
            float4 v = src[f4i];
            int l = f4i >> 4, k4 = (f4i & 15) << 2;
            pl[l][k4+0] = v.x; pl[l][k4+1] = v.y; pl[l][k4+2] = v.z; pl[l][k4+3] = v.w;
        }
    }
    {
        #pragma unroll
        for (int i = 0; i < 4; ++i) {
            int f4i = tid + 256 * i;
            int k = f4i >> 4, m4 = (f4i & 15) << 2;
            float4 v = *(const float4*)(Wdt + (size_t)k * 1024 + d0 + m4);
            *(float4*)&wl[k][m4] = v;
        }
    }
    __syncthreads();

    const int lsub = tid & 63;
    const int dq = tid >> 6;
    float acc[16];
    #pragma unroll
    for (int i = 0; i < 16; ++i) acc[i] = 0.f;

    #pragma unroll 4
    for (int k = 0; k < 64; ++k) {
        float p = pl[lsub][k];
        const float4* wr = (const float4*)&wl[k][dq * 16];
        float4 w0 = wr[0], w1 = wr[1], w2 = wr[2], w3 = wr[3];
        acc[0]  = fmaf(p, w0.x, acc[0]);  acc[1]  = fmaf(p, w0.y, acc[1]);
        acc[2]  = fmaf(p, w0.z, acc[2]);  acc[3]  = fmaf(p, w0.w, acc[3]);
        acc[4]  = fmaf(p, w1.x, acc[4]);  acc[5]  = fmaf(p, w1.y, acc[5]);
        acc[6]  = fmaf(p, w1.z, acc[6]);  acc[7]  = fmaf(p, w1.w, acc[7]);
        acc[8]  = fmaf(p, w2.x, acc[8]);  acc[9]  = fmaf(p, w2.y, acc[9]);
        acc[10] = fmaf(p, w2.z, acc[10]); acc[11] = fmaf(p, w2.w, acc[11]);
        acc[12] = fmaf(p, w3.x, acc[12]); acc[13] = fmaf(p, w3.y, acc[13]);
        acc[14] = fmaf(p, w3.z, acc[14]); acc[15] = fmaf(p, w3.w, acc[15]);
    }

    #pragma unroll
    for (int i = 0; i < 16; ++i) {
        float v = acc[i] + bdt[d0 + dq * 16 + i];
        float sp = fmaxf(v, 0.f) + log1pf(__expf(-fabsf(v)));
        dtile[dq * 16 + i][lsub] = sp;
    }
    __syncthreads();

    {
        int dp_ = tid >> 2, seg = tid & 3;
        int b = row0 >> 10, l0 = row0 & 1023;
        float* dst = delta_t + ((size_t)b * 1024 + d0 + dp_) * 1024 + l0 + seg * 16;
        #pragma unroll
        for (int m = 0; m < 4; ++m) {
            float4 v;
            v.x = dtile[dp_][seg*16 + m*4 + 0];
            v.y = dtile[dp_][seg*16 + m*4 + 1];
            v.z = dtile[dp_][seg*16 + m*4 + 2];
            v.w = dtile[dp_][seg*16 + m*4 + 3];
            ((float4*)dst)[m] = v;
        }
    }
}

// ============ Kernel 3: wave-parallel clamped scan, 4-way state split ============
// Block (256 thr = 4 waves) = ONE (b,d) chain; wave q owns states n0=4q..4q+3.
// Lane i owns l in [16i, 16i+16). Final y summed over waves via LDS.
__global__ __launch_bounds__(256) void scan_kernel(
        const float* __restrict__ delta_t, const float* __restrict__ x,
        const float* __restrict__ Bg, const float* __restrict__ Cg,
        const float* __restrict__ A_log, const float* __restrict__ Dvec,
        float* __restrict__ y) {
    const int bid0 = blockIdx.x;                       // 0..2047
    const int bid  = (bid0 & 7) * 256 + (bid0 >> 3);   // XCD-chunked swizzle
    const int b = bid >> 10;
    const int d = bid & 1023;
    const int lane = threadIdx.x & 63;
    const int q = threadIdx.x >> 6;                    // 0..3
    const int n0 = q * 4;

    __shared__ float ucol[1024 + 64];                  // idx = l + (l>>4), bank-bijective
    __shared__ float ylds[4][16][64];                  // [wave][i][lane]

    const float* dtp  = delta_t + ((size_t)b * 1024 + d) * 1024;
    const float* xcol = x + (size_t)b * 1024 * 1024 + d;

    {   // stage u = delta * x once per block
        int l0s = threadIdx.x * 4;
        float4 dl = *(const float4*)(dtp + l0s);
        float x0 = xcol[(size_t)(l0s + 0) * 1024];
        float x1 = xcol[(size_t)(l0s + 1) * 1024];
        float x2 = xcol[(size_t)(l0s + 2) * 1024];
        float x3 = xcol[(size_t)(l0s + 3) * 1024];
        float4 uv = make_float4(dl.x * x0, dl.y * x1, dl.z * x2, dl.w * x3);
        *(float4*)&ucol[l0s + (l0s >> 4)] = uv;
    }

    float A[4];
    #pragma unroll
    for (int jn = 0; jn < 4; ++jn)
        A[jn] = -__expf(A_log[d * 16 + n0 + jn]);

    const float* dlp = dtp + lane * 16;
    const float* Bp  = Bg + ((size_t)b * 16 + n0) * 1024 + lane * 16;
    const float* Cp  = Cg + ((size_t)b * 16 + n0) * 1024 + lane * 16;

    __syncthreads();

    float coff[4], soff[4], cum[4], S[4];

    // ---- pass 1: per-lane p-sums ----
    #pragma unroll
    for (int jn = 0; jn < 4; ++jn) coff[jn] = 0.f;
    #pragma unroll
    for (int w = 0; w < 4; ++w) {
        float4 d4 = ((const float4*)dlp)[w];
        #pragma unroll
        for (int jn = 0; jn < 4; ++jn) {
            float a = A[jn], s = coff[jn];
            s += fmaxf(d4.x * a, -7.f);
            s += fmaxf(d4.y * a, -7.f);
            s += fmaxf(d4.z * a, -7.f);
            s += fmaxf(d4.w * a, -7.f);
            coff[jn] = s;
        }
    }
    #pragma unroll
    for (int jn = 0; jn < 4; ++jn) {
        float v = coff[jn];
        #pragma unroll
        for (int off = 1; off < 64; off <<= 1) {
            float t = __shfl_up(v, off);
            v += (lane >= off) ? t : 0.f;
        }
        float e = __shfl_up(v, 1);
        coff[jn] = (lane > 0) ? e : 0.f;
    }

    // ---- pass 2: per-lane q-sums with stitched cum ----
    #pragma unroll
    for (int jn = 0; jn < 4; ++jn) { cum[jn] = coff[jn]; soff[jn] = 0.f; }
    #pragma unroll 1
    for (int w = 0; w < 4; ++w) {
        float4 d4 = ((const float4*)dlp)[w];
        float4 u4 = *(const float4*)&ucol[lane * 17 + w * 4];
        #pragma unroll
        for (int jn = 0; jn < 4; ++jn) {
            float4 b4 = *(const float4*)(Bp + (size_t)jn * 1024 + w * 4);
            float a = A[jn];
            float c = cum[jn], qq = soff[jn];
            c += fmaxf(d4.x * a, -7.f);
            qq = fmaf(u4.x * b4.x, __expf(fminf(-c, 20.f)), qq);
            c += fmaxf(d4.y * a, -7.f);
            qq = fmaf(u4.y * b4.y, __expf(fminf(-c, 20.f)), qq);
            c += fmaxf(d4.z * a, -7.f);
            qq = fmaf(u4.z * b4.z, __expf(fminf(-c, 20.f)), qq);
            c += fmaxf(d4.w * a, -7.f);
            qq = fmaf(u4.w * b4.w, __expf(fminf(-c, 20.f)), qq);
            cum[jn] = c; soff[jn] = qq;
        }
    }
    #pragma unroll
    for (int jn = 0; jn < 4; ++jn) {
        float v = soff[jn];
        #pragma unroll
        for (int off = 1; off < 64; off <<= 1) {
            float t = __shfl_up(v, off);
            v += (lane >= off) ? t : 0.f;
        }
        float e = __shfl_up(v, 1);
        soff[jn] = (lane > 0) ? e : 0.f;
    }

    // ---- pass 3: final walk, y partials into LDS ----
    #pragma unroll
    for (int jn = 0; jn < 4; ++jn) { cum[jn] = coff[jn]; S[jn] = soff[jn]; }
    #pragma unroll 1
    for (int w = 0; w < 4; ++w) {
        float4 d4 = ((const float4*)dlp)[w];
        float4 u4 = *(const float4*)&ucol[lane * 17 + w * 4];
        float y0 = 0.f, y1 = 0.f, y2 = 0.f, y3 = 0.f;
        #pragma unroll
        for (int jn = 0; jn < 4; ++jn) {
            float4 b4 = *(const float4*)(Bp + (size_t)jn * 1024 + w * 4);
            float4 c4 = *(const float4*)(Cp + (size_t)jn * 1024 + w * 4);
            float a = A[jn];
            float c = cum[jn], s = S[jn];

            c += fmaxf(d4.x * a, -7.f);
            s = fmaf(u4.x * b4.x, __expf(fminf(-c, 20.f)), s);
            y0 = fmaf(c4.x * __expf(c), s, y0);

            c += fmaxf(d4.y * a, -7.f);
            s = fmaf(u4.y * b4.y, __expf(fminf(-c, 20.f)), s);
            y1 = fmaf(c4.y * __expf(c), s, y1);

            c += fmaxf(d4.z * a, -7.f);
            s = fmaf(u4.z * b4.z, __expf(fminf(-c, 20.f)), s);
            y2 = fmaf(c4.z * __expf(c), s, y2);

            c += fmaxf(d4.w * a, -7.f);
            s = fmaf(u4.w * b4.w, __expf(fminf(-c, 20.f)), s);
            y3 = fmaf(c4.w * __expf(c), s, y3);

            cum[jn] = c; S[jn] = s;
        }
        ylds[q][w * 4 + 0][lane] = y0;
        ylds[q][w * 4 + 1][lane] = y1;
        ylds[q][w * 4 + 2][lane] = y2;
        ylds[q][w * 4 + 3][lane] = y3;
    }
    __syncthreads();

    // ---- reduce over waves + write; wave q handles i = 4q..4q+3 ----
    const float Dd = Dvec[d];
    #pragma unroll
    for (int ii = 0; ii < 4; ++ii) {
        int i = q * 4 + ii;
        float v = ylds[0][i][lane] + ylds[1][i][lane]
                + ylds[2][i][lane] + ylds[3][i][lane];
        int l = lane * 16 + i;
        float xv = xcol[(size_t)l * 1024];
        y[(size_t)b * 1024 * 1024 + (size_t)l * 1024 + d] = fmaf(xv, Dd, v);
    }
}

extern "C" void kernel_launch(void* const* d_in, const int* in_sizes, int n_in,
                              void* d_out, int out_size, void* d_ws, size_t ws_size,
                              hipStream_t stream) {
    const float* x    = (const float*)d_in[0];
    const float* Wx   = (const float*)d_in[1];
    const float* Wdt  = (const float*)d_in[2];
    const float* bdt  = (const float*)d_in[3];
    const float* Alog = (const float*)d_in[4];
    const float* Dvec = (const float*)d_in[5];
    float* y = (float*)d_out;

    float* projdt  = (float*)d_ws;
    float* Bgp     = projdt + (size_t)2048 * 64;
    float* Cgp     = Bgp + (size_t)2 * 16 * 1024;
    float* delta_t = Cgp + (size_t)2 * 16 * 1024;

    proj_kernel<<<256, 768, 0, stream>>>(x, Wx, projdt, Bgp, Cgp);
    delta_kernel<<<512, 256, 0, stream>>>(projdt, Wdt, bdt, delta_t);
    scan_kernel<<<2048, 256, 0, stream>>>(delta_t, x, Bgp, Cgp, Alog, Dvec, y);
}

// Round 4
// 113.478 us; speedup vs baseline: 1.0961x; 1.0961x over previous
//
#include <hip/hip_runtime.h>
#include <math.h>

#define D_INNER 1024
#define STATE   16
#define DT_RANK 64
#define NPROJ   96
#define LSEQ    1024
#define NBATCH  2

// ============ Kernel 1: proj = x @ W_xproj ============
// 256 blocks x 768 threads; 8 rows/block, K split across 8 groups of 128.
__global__ __launch_bounds__(768) void proj_kernel(
        const float* __restrict__ x, const float* __restrict__ Wx,
        float* __restrict__ projdt, float* __restrict__ Bg, float* __restrict__ Cg) {
    const int tid = threadIdx.x;
    const int j  = tid % 96;
    const int kq = tid / 96;              // 0..7
    const int row0 = blockIdx.x * 8;

    const float* wp = Wx + (size_t)(kq * 128) * 96 + j;
    const float* xb = x + (size_t)row0 * 1024 + kq * 128;

    float a[8];
    #pragma unroll
    for (int r = 0; r < 8; ++r) a[r] = 0.f;

    #pragma unroll 4
    for (int k = 0; k < 128; k += 4) {
        float4 xr[8];
        #pragma unroll
        for (int r = 0; r < 8; ++r)
            xr[r] = *(const float4*)(xb + (size_t)r * 1024 + k);
        #pragma unroll
        for (int kk = 0; kk < 4; ++kk) {
            float w = wp[(size_t)(k + kk) * 96];
            #pragma unroll
            for (int r = 0; r < 8; ++r) {
                float xv = (kk == 0) ? xr[r].x : (kk == 1) ? xr[r].y
                         : (kk == 2) ? xr[r].z : xr[r].w;
                a[r] = fmaf(xv, w, a[r]);
            }
        }
    }

    __shared__ float red[8][8][96];       // [kq][r][j] = 24 KB
    #pragma unroll
    for (int r = 0; r < 8; ++r) red[kq][r][j] = a[r];
    __syncthreads();

    {   // 768 outputs, one per thread
        const int r  = tid / 96;
        const int jj = tid % 96;
        float s = 0.f;
        #pragma unroll
        for (int p = 0; p < 8; ++p) s += red[p][r][jj];
        const int row = row0 + r;
        const int b = row >> 10, l = row & 1023;
        if (jj < 64)      projdt[(size_t)row * 64 + jj] = s;
        else if (jj < 80) Bg[((size_t)b * 16 + (jj - 64)) * 1024 + l] = s;
        else              Cg[((size_t)b * 16 + (jj - 80)) * 1024 + l] = s;
    }
}

// ============ Kernel 2: delta = softplus(projdt @ W_dt + b_dt), transposed out ====
__global__ __launch_bounds__(256) void delta_kernel(
        const float* __restrict__ projdt, const float* __restrict__ Wdt,
        const float* __restrict__ bdt, float* __restrict__ delta_t) {
    const int bid = blockIdx.x;
    const int lt = bid >> 4;
    const int dt = bid & 15;
    const int row0 = lt * 64;
    const int d0 = dt * 64;
    const int tid = threadIdx.x;

    __shared__ float pl[64][69];
    __shared__ float wl[64][68];
    __shared__ float dtile[64][65];

    {
        const float4* src = (const float4*)(projdt + (size_t)row0 * 64);
        #pragma unroll
        for (int i = 0; i < 4; ++i) {
            int f4i = tid + 256 * i;
            float4 v = src[f4i];
            int l = f4i >> 4, k4 = (f4i & 15) << 2;
            pl[l][k4+0] = v.x; pl[l][k4+1] = v.y; pl[l][k4+2] = v.z; pl[l][k4+3] = v.w;
        }
    }
    {
        #pragma unroll
        for (int i = 0; i < 4; ++i) {
            int f4i = tid + 256 * i;
            int k = f4i >> 4, m4 = (f4i & 15) << 2;
            float4 v = *(const float4*)(Wdt + (size_t)k * 1024 + d0 + m4);
            *(float4*)&wl[k][m4] = v;
        }
    }
    __syncthreads();

    const int lsub = tid & 63;
    const int dq = tid >> 6;
    float acc[16];
    #pragma unroll
    for (int i = 0; i < 16; ++i) acc[i] = 0.f;

    #pragma unroll 4
    for (int k = 0; k < 64; ++k) {
        float p = pl[lsub][k];
        const float4* wr = (const float4*)&wl[k][dq * 16];
        float4 w0 = wr[0], w1 = wr[1], w2 = wr[2], w3 = wr[3];
        acc[0]  = fmaf(p, w0.x, acc[0]);  acc[1]  = fmaf(p, w0.y, acc[1]);
        acc[2]  = fmaf(p, w0.z, acc[2]);  acc[3]  = fmaf(p, w0.w, acc[3]);
        acc[4]  = fmaf(p, w1.x, acc[4]);  acc[5]  = fmaf(p, w1.y, acc[5]);
        acc[6]  = fmaf(p, w1.z, acc[6]);  acc[7]  = fmaf(p, w1.w, acc[7]);
        acc[8]  = fmaf(p, w2.x, acc[8]);  acc[9]  = fmaf(p, w2.y, acc[9]);
        acc[10] = fmaf(p, w2.z, acc[10]); acc[11] = fmaf(p, w2.w, acc[11]);
        acc[12] = fmaf(p, w3.x, acc[12]); acc[13] = fmaf(p, w3.y, acc[13]);
        acc[14] = fmaf(p, w3.z, acc[14]); acc[15] = fmaf(p, w3.w, acc[15]);
    }

    #pragma unroll
    for (int i = 0; i < 16; ++i) {
        float v = acc[i] + bdt[d0 + dq * 16 + i];
        float sp = fmaxf(v, 0.f) + log1pf(__expf(-fabsf(v)));
        dtile[dq * 16 + i][lsub] = sp;
    }
    __syncthreads();

    {
        int dp_ = tid >> 2, seg = tid & 3;
        int b = row0 >> 10, l0 = row0 & 1023;
        float* dst = delta_t + ((size_t)b * 1024 + d0 + dp_) * 1024 + l0 + seg * 16;
        #pragma unroll
        for (int m = 0; m < 4; ++m) {
            float4 v;
            v.x = dtile[dp_][seg*16 + m*4 + 0];
            v.y = dtile[dp_][seg*16 + m*4 + 1];
            v.z = dtile[dp_][seg*16 + m*4 + 2];
            v.w = dtile[dp_][seg*16 + m*4 + 3];
            ((float4*)dst)[m] = v;
        }
    }
}

// ============ Kernel 3: wave-parallel clamped scan, 4-way L split ============
// Block (256 thr = 4 waves) = ONE (b,d) chain. Wave q owns l in [256q,256q+256);
// lane owns 4 consecutive l. All 16 states in registers per lane.
// Cross-wave stitch of the two cumsums via 512B LDS totals (2 barriers).
__global__ __launch_bounds__(256) void scan_kernel(
        const float* __restrict__ delta_t, const float* __restrict__ x,
        const float* __restrict__ Bg, const float* __restrict__ Cg,
        const float* __restrict__ A_log, const float* __restrict__ Dvec,
        float* __restrict__ y) {
    const int bid0 = blockIdx.x;                       // 0..2047
    const int bid  = (bid0 & 7) * 256 + (bid0 >> 3);   // XCD-chunked swizzle
    const int b = bid >> 10;
    const int d = bid & 1023;
    const int lane = threadIdx.x & 63;
    const int q = threadIdx.x >> 6;                    // L-quarter 0..3
    const int l0 = q * 256 + lane * 4;                 // this lane's 4 l's

    __shared__ float tot1[16][4];
    __shared__ float tot2[16][4];

    const float* dlp = delta_t + ((size_t)b * 1024 + d) * 1024 + l0;
    const float* xp  = x + ((size_t)b * 1024 + l0) * 1024 + d;
    const float* Bp  = Bg + (size_t)b * 16 * 1024 + l0;
    const float* Cp  = Cg + (size_t)b * 16 * 1024 + l0;

    float A[16];
    #pragma unroll
    for (int n = 0; n < 16; ++n) A[n] = -__expf(A_log[d * 16 + n]);

    const float4 d4 = *(const float4*)dlp;
    const float x0 = xp[0], x1 = xp[1024], x2 = xp[2048], x3 = xp[3072];
    const float u0 = d4.x * x0, u1 = d4.y * x1, u2 = d4.z * x2, u3 = d4.w * x3;

    // ---- pass 1: p-cumsum (log_dA), lane-scan + wave-stitch ----
    float coff[16];
    #pragma unroll
    for (int n = 0; n < 16; ++n) {
        float a = A[n];
        float s = fmaxf(d4.x * a, -7.f) + fmaxf(d4.y * a, -7.f)
                + fmaxf(d4.z * a, -7.f) + fmaxf(d4.w * a, -7.f);
        float v = s;
        #pragma unroll
        for (int off = 1; off < 64; off <<= 1) {
            float t = __shfl_up(v, off);
            v += (lane >= off) ? t : 0.f;
        }
        if (lane == 63) tot1[n][q] = v;
        float e = __shfl_up(v, 1);
        coff[n] = (lane > 0) ? e : 0.f;
    }
    __syncthreads();
    #pragma unroll
    for (int n = 0; n < 16; ++n) {
        float w = 0.f;
        if (q > 0) w += tot1[n][0];
        if (q > 1) w += tot1[n][1];
        if (q > 2) w += tot1[n][2];
        coff[n] += w;                 // global exclusive prefix of log_dA
    }

    // ---- pass 2: q-cumsum (delta_B_u * exp(min(-log_R,20))) ----
    float soff[16];
    #pragma unroll
    for (int n = 0; n < 16; ++n) {
        float a = A[n];
        float4 b4 = *(const float4*)(Bp + (size_t)n * 1024);
        float c = coff[n];
        float t;
        c += fmaxf(d4.x * a, -7.f);
        t  = u0 * b4.x * __expf(fminf(-c, 20.f));
        c += fmaxf(d4.y * a, -7.f);
        t  = fmaf(u1 * b4.y, __expf(fminf(-c, 20.f)), t);
        c += fmaxf(d4.z * a, -7.f);
        t  = fmaf(u2 * b4.z, __expf(fminf(-c, 20.f)), t);
        c += fmaxf(d4.w * a, -7.f);
        t  = fmaf(u3 * b4.w, __expf(fminf(-c, 20.f)), t);
        float v = t;
        #pragma unroll
        for (int off = 1; off < 64; off <<= 1) {
            float tt = __shfl_up(v, off);
            v += (lane >= off) ? tt : 0.f;
        }
        if (lane == 63) tot2[n][q] = v;
        float e = __shfl_up(v, 1);
        soff[n] = (lane > 0) ? e : 0.f;
    }
    __syncthreads();
    #pragma unroll
    for (int n = 0; n < 16; ++n) {
        float w = 0.f;
        if (q > 0) w += tot2[n][0];
        if (q > 1) w += tot2[n][1];
        if (q > 2) w += tot2[n][2];
        soff[n] += w;                 // global exclusive prefix of S-terms
    }

    // ---- pass 3: final walk, accumulate y over n in-register ----
    const float Dd = Dvec[d];
    float y0 = x0 * Dd, y1 = x1 * Dd, y2 = x2 * Dd, y3 = x3 * Dd;
    #pragma unroll
    for (int n = 0; n < 16; ++n) {
        float a = A[n];
        float4 b4 = *(const float4*)(Bp + (size_t)n * 1024);
        float4 c4 = *(const float4*)(Cp + (size_t)n * 1024);
        float c = coff[n], s = soff[n];

        c += fmaxf(d4.x * a, -7.f);
        s  = fmaf(u0 * b4.x, __expf(fminf(-c, 20.f)), s);
        y0 = fmaf(c4.x * __expf(c), s, y0);

        c += fmaxf(d4.y * a, -7.f);
        s  = fmaf(u1 * b4.y, __expf(fminf(-c, 20.f)), s);
        y1 = fmaf(c4.y * __expf(c), s, y1);

        c += fmaxf(d4.z * a, -7.f);
        s  = fmaf(u2 * b4.z, __expf(fminf(-c, 20.f)), s);
        y2 = fmaf(c4.z * __expf(c), s, y2);

        c += fmaxf(d4.w * a, -7.f);
        s  = fmaf(u3 * b4.w, __expf(fminf(-c, 20.f)), s);
        y3 = fmaf(c4.w * __expf(c), s, y3);
    }

    float* yp = y + ((size_t)b * 1024 + l0) * 1024 + d;
    yp[0]    = y0;
    yp[1024] = y1;
    yp[2048] = y2;
    yp[3072] = y3;
}

extern "C" void kernel_launch(void* const* d_in, const int* in_sizes, int n_in,
                              void* d_out, int out_size, void* d_ws, size_t ws_size,
                              hipStream_t stream) {
    const float* x    = (const float*)d_in[0];
    const float* Wx   = (const float*)d_in[1];
    const float* Wdt  = (const float*)d_in[2];
    const float* bdt  = (const float*)d_in[3];
    const float* Alog = (const float*)d_in[4];
    const float* Dvec = (const float*)d_in[5];
    float* y = (float*)d_out;

    float* projdt  = (float*)d_ws;
    float* Bgp     = projdt + (size_t)2048 * 64;
    float* Cgp     = Bgp + (size_t)2 * 16 * 1024;
    float* delta_t = Cgp + (size_t)2 * 16 * 1024;

    proj_kernel<<<256, 768, 0, stream>>>(x, Wx, projdt, Bgp, Cgp);
    delta_kernel<<<512, 256, 0, stream>>>(projdt, Wdt, bdt, delta_t);
    scan_kernel<<<2048, 256, 0, stream>>>(delta_t, x, Bgp, Cgp, Alog, Dvec, y);
}